// Round 3
// baseline (10912.048 us; speedup 1.0000x reference)
//
#include <hip/hip_runtime.h>
#include <math.h>

#define HD 512
#define NB 32
#define LS 2048
#define SYNC_OFF (65536 + 3 * HD * HD)  // float offset of sync area in ws

// Swizzled LDS h-tile: 16 rows; each row = 16 k-blocks of 32 floats, each
// k-block padded to 36 floats (144 B) so the stride-128B ks read pattern
// spreads across banks instead of a 16-way conflict.
#define HSTRIDE 576                      // floats per LDS h row (16*36)
#define PART_F 4608                      // 128*36 partial floats per sub-block
#define SMEM_FLOATS (2 * PART_F + 2 * 16 * HSTRIDE)  // 9216 + 18432 = 27648
#define SMEM_BYTES (SMEM_FLOATS * 4)                 // 110592

typedef float f32x4 __attribute__((ext_vector_type(4)));

// ---------------------------------------------------------------------------
// Kernel 1 (unchanged, known-good): Xi = x @ Wi0 + bi0 into d_out's [B,L,H].
// ---------------------------------------------------------------------------
__global__ __launch_bounds__(256) void xi_gemm(const float* __restrict__ x,
                                               const float* __restrict__ Wi0,
                                               const float* __restrict__ bi0,
                                               float* __restrict__ out) {
  __shared__ float As[16][68];
  __shared__ float Bs[16][68];
  const int bn = blockIdx.x * 64;
  const int bm = blockIdx.y * 64;
  const int tid = threadIdx.x;
  const int tm = (tid & 15) * 4;
  const int tn = (tid >> 4) * 4;
  float acc[4][4] = {};
  for (int k0 = 0; k0 < HD; k0 += 16) {
    {
      const int r = tid >> 2, ks = (tid & 3) * 4;
      const float4 av = *(const float4*)(x + (size_t)(bm + r) * HD + k0 + ks);
      As[ks + 0][r] = av.x; As[ks + 1][r] = av.y;
      As[ks + 2][r] = av.z; As[ks + 3][r] = av.w;
      const int kk = tid >> 4, ns = (tid & 15) * 4;
      *(float4*)&Bs[kk][ns] = *(const float4*)(Wi0 + (size_t)(k0 + kk) * HD + bn + ns);
    }
    __syncthreads();
#pragma unroll
    for (int k = 0; k < 16; ++k) {
      const float4 a = *(const float4*)&As[k][tm];
      const float4 b = *(const float4*)&Bs[k][tn];
      acc[0][0] = fmaf(a.x, b.x, acc[0][0]); acc[0][1] = fmaf(a.x, b.y, acc[0][1]);
      acc[0][2] = fmaf(a.x, b.z, acc[0][2]); acc[0][3] = fmaf(a.x, b.w, acc[0][3]);
      acc[1][0] = fmaf(a.y, b.x, acc[1][0]); acc[1][1] = fmaf(a.y, b.y, acc[1][1]);
      acc[1][2] = fmaf(a.y, b.z, acc[1][2]); acc[1][3] = fmaf(a.y, b.w, acc[1][3]);
      acc[2][0] = fmaf(a.z, b.x, acc[2][0]); acc[2][1] = fmaf(a.z, b.y, acc[2][1]);
      acc[2][2] = fmaf(a.z, b.z, acc[2][2]); acc[2][3] = fmaf(a.z, b.w, acc[2][3]);
      acc[3][0] = fmaf(a.w, b.x, acc[3][0]); acc[3][1] = fmaf(a.w, b.y, acc[3][1]);
      acc[3][2] = fmaf(a.w, b.z, acc[3][2]); acc[3][3] = fmaf(a.w, b.w, acc[3][3]);
    }
    __syncthreads();
  }
  const float4 bias = *(const float4*)(bi0 + bn + tn);
#pragma unroll
  for (int i = 0; i < 4; ++i) {
    float4 v;
    v.x = acc[i][0] + bias.x; v.y = acc[i][1] + bias.y;
    v.z = acc[i][2] + bias.z; v.w = acc[i][3] + bias.w;
    *(float4*)(out + (size_t)(bm + tm + i) * HD + bn + tn) = v;
  }
}

// ---------------------------------------------------------------------------
// Kernel 2 (unchanged): WT[z][c][k] = W_z[k][c], z in {Wh0, Wi1, Wh1}.
// ---------------------------------------------------------------------------
__global__ void transpose_w(const float* __restrict__ Wh0,
                            const float* __restrict__ Wi1,
                            const float* __restrict__ Wh1,
                            float* __restrict__ WT) {
  const int k = blockIdx.y;
  const int c = (blockIdx.x << 8) + threadIdx.x;
  const int z = blockIdx.z;
  const float* src = (z == 0) ? Wh0 : (z == 1) ? Wi1 : Wh1;
  WT[(size_t)z * HD * HD + (size_t)c * HD + k] = src[(size_t)k * HD + c];
}

// ---------------------------------------------------------------------------
// Kernel 3 (unchanged): init h dbufs (parity 1 = h[-1]) + zero sync area.
// ---------------------------------------------------------------------------
__global__ void init_h(const float* __restrict__ h0, float* __restrict__ ws) {
  const int i = blockIdx.x * 256 + threadIdx.x;  // [0, 32768)
  const float v = h0[i];
  if (i < 16384) ws[16384 + i] = v;                   // layer 0, parity 1
  else           ws[32768 + 16384 + (i - 16384)] = v; // layer 1, parity 1
  if (blockIdx.x == 0) {
    unsigned* syncp = (unsigned*)(ws + SYNC_OFF);
    syncp[threadIdx.x] = 0;
  }
}

// ---------------------------------------------------------------------------
// swz: float4 index [0,2048) of an 8192-float h slice -> swizzled LDS float
// offset.
// ---------------------------------------------------------------------------
__device__ __forceinline__ int swz(int idx) {
  const int row = idx >> 7, f4 = idx & 127;
  return row * HSTRIDE + (f4 >> 3) * 36 + (f4 & 7) * 4;
}

// Coherent 16B load / store (sc1 = device-coherent point; proven pattern).
#define LDG_C(dst, p) \
  asm volatile("global_load_dwordx4 %0, %1, off sc1" : "=v"(dst) : "v"(p))
#define STG_C(p, v) \
  asm volatile("global_store_dwordx4 %0, %1, off sc1" :: "v"(p), "v"(v) : "memory")

// ---------------------------------------------------------------------------
// All-wave stamp poll, NO barrier. Every wave polls the 32 stamps of one
// (layer,group) line (lanes l and l+32 duplicate stamp l&31) until __all
// pass. Replaces wave0-poll + __syncthreads: each wave proceeds as soon as
// the condition holds, removing barrier propagation from the wait path.
// SAFETY for the following LDS writes: the polled set includes our OWN
// block's stamp, which is published only after the previous iteration's
// end-of-step __syncthreads — so a fast wave cannot overwrite LDS that a
// slow sibling wave is still reading.
// ---------------------------------------------------------------------------
__device__ __forceinline__ void wave_poll(const unsigned* a, int ta) {
  const unsigned* p = a + (threadIdx.x & 31);
  for (;;) {
    const int sv = (int)__hip_atomic_load(p, __ATOMIC_RELAXED,
                                          __HIP_MEMORY_SCOPE_AGENT);
    if (__all(sv >= ta)) break;
    __builtin_amdgcn_s_sleep(1);
  }
}

// ---------------------------------------------------------------------------
// Kernel 4: persistent recurrence, 128 blocks x 512 threads.
// Round-3 latency surgery (same stamp semantics as the passing round-2):
//  - all-wave polling (no barrier in the wait path)
//  - L1: h1[t-1] staging loads issue BEFORE the L0-stamp wait (own-stamp
//    guarded), hiding one load round trip under the poll
//  - L0: backpressure check (stampL1 >= t-1) moved AFTER compute — it only
//    guards the h-store, not the stage/read
//  - L0: in-wave __shfl_xor butterfly over the 16 k-slices replaces the
//    part-LDS round trip + one barrier; float4 h stores (16 vs 128 reqs)
// Dependency/overwrite arguments identical to round 2:
//  L0 step t: stage needs stampL0 >= t; store needs stampL1 >= t-1.
//  L1 step t: h1 read needs stampL1 >= t; h0 read needs stampL0 >= t+1.
//  Own-layer stamp gates all intra-layer buffer overwrites.
// ---------------------------------------------------------------------------
__global__ __launch_bounds__(512, 2) void rnn_persist(
    const float* __restrict__ WT,
    const float* __restrict__ bh0,
    const float* __restrict__ bi1,
    const float* __restrict__ bh1,
    float* __restrict__ outbuf,
    float* __restrict__ ws) {
  extern __shared__ float smem[];

  const int tid = threadIdx.x;
  const int bid = blockIdx.x;
  const int g = bid & 1;
  const int layer = (bid >> 1) & 1;
  const int cb2 = bid >> 2;          // [0,32)
  const int sb = tid >> 8;           // sub-block 0/1
  const int st = tid & 255;
  const int col0 = (cb2 * 2 + sb) * 8;
  const int bbase = g * 16;

  float* part = smem + sb * PART_F;
  float* hst0 = smem + 2 * PART_F;
  float* hst1 = hst0 + 16 * HSTRIDE;

  float* h0b = ws;
  float* h1b = ws + 32768;
  unsigned* syncp = (unsigned*)(ws + SYNC_OFF);
  unsigned* stampL0 = syncp + g * 32;
  unsigned* stampL1 = syncp + 64 + g * 32;
  const size_t OUT0 = (size_t)NB * LS * HD;

  if (layer == 0) {
    const int cg = st & 1;                 // 2 col-groups of 4
    const int ks = (st >> 1) & 15;         // 16 k-slices of 32
    const int kb = ks * 32;
    const int bg = st >> 5;                // 8 b-groups of 2
    const bool act = (ks == 0);            // lanes {0,1,32,33} of each wave
    const int fb2 = bbase + bg * 2;        // batch base of this lane's outputs
    float4 w[4][8];
#pragma unroll
    for (int ci = 0; ci < 4; ++ci)
#pragma unroll
      for (int kk = 0; kk < 8; ++kk)
        w[ci][kk] = *(const float4*)(WT + (size_t)(col0 + cg * 4 + ci) * HD + kb + kk * 4);
    const float4 bias4 = *(const float4*)(bh0 + col0 + cg * 4);

    for (int t = 0; t < LS; ++t) {
      // Xi prefetch (plain cached) by output-owning lanes; hazard-free:
      // L1 overwrites out[b,t,:] only after ALL L0 stamps >= t+1.
      f32x4 xi0 = {0.f, 0.f, 0.f, 0.f}, xi1 = {0.f, 0.f, 0.f, 0.f};
      if (act) {
        xi0 = *(const f32x4*)(outbuf + ((size_t)(fb2 + 0) * LS + t) * HD + col0 + cg * 4);
        xi1 = *(const f32x4*)(outbuf + ((size_t)(fb2 + 1) * LS + t) * HD + col0 + cg * 4);
      }

      wave_poll(stampL0, t);               // h0[t-1] published by all L0(g)
      {  // stage h0[t-1] -> hst0 (coalesced 16B sc1 loads, swizzled LDS)
        const float* src = h0b + ((t + 1) & 1) * 16384 + bbase * HD;
        f32x4 a, b, c, d;
        LDG_C(a, src + ((0 * 512 + tid) << 2));
        LDG_C(b, src + ((1 * 512 + tid) << 2));
        LDG_C(c, src + ((2 * 512 + tid) << 2));
        LDG_C(d, src + ((3 * 512 + tid) << 2));
        asm volatile("s_waitcnt vmcnt(0)" ::: "memory");
        *(f32x4*)&hst0[swz(0 * 512 + tid)] = a;
        *(f32x4*)&hst0[swz(1 * 512 + tid)] = b;
        *(f32x4*)&hst0[swz(2 * 512 + tid)] = c;
        *(f32x4*)&hst0[swz(3 * 512 + tid)] = d;
      }
      __syncthreads();

      const float* rA = hst0 + (bg * 2) * HSTRIDE + ks * 36;
      const float* rB = rA + HSTRIDE;
      float acc[4][2] = {};
#pragma unroll
      for (int kk = 0; kk < 8; ++kk) {
        const float4 a4 = *(const float4*)(rA + kk * 4);
        const float4 b4 = *(const float4*)(rB + kk * 4);
#pragma unroll
        for (int ci = 0; ci < 4; ++ci) {
          const float4 wv = w[ci][kk];
          acc[ci][0] = fmaf(wv.x, a4.x, acc[ci][0]);
          acc[ci][0] = fmaf(wv.y, a4.y, acc[ci][0]);
          acc[ci][0] = fmaf(wv.z, a4.z, acc[ci][0]);
          acc[ci][0] = fmaf(wv.w, a4.w, acc[ci][0]);
          acc[ci][1] = fmaf(wv.x, b4.x, acc[ci][1]);
          acc[ci][1] = fmaf(wv.y, b4.y, acc[ci][1]);
          acc[ci][1] = fmaf(wv.z, b4.z, acc[ci][1]);
          acc[ci][1] = fmaf(wv.w, b4.w, acc[ci][1]);
        }
      }
      // Butterfly sum over ks (tid bits 1-4 = lane bits 1-4, intra-wave).
#pragma unroll
      for (int mask = 2; mask <= 16; mask <<= 1)
#pragma unroll
        for (int ci = 0; ci < 4; ++ci) {
          acc[ci][0] += __shfl_xor(acc[ci][0], mask, 64);
          acc[ci][1] += __shfl_xor(acc[ci][1], mask, 64);
        }

      // Backpressure (guards only the h-store): L1 done reading h0[t-2].
      wave_poll(stampL1, t - 1);

      if (act) {
        f32x4 h0v, h1v;
        h0v.x = tanhf(acc[0][0] + xi0.x + bias4.x);
        h0v.y = tanhf(acc[1][0] + xi0.y + bias4.y);
        h0v.z = tanhf(acc[2][0] + xi0.z + bias4.z);
        h0v.w = tanhf(acc[3][0] + xi0.w + bias4.w);
        h1v.x = tanhf(acc[0][1] + xi1.x + bias4.x);
        h1v.y = tanhf(acc[1][1] + xi1.y + bias4.y);
        h1v.z = tanhf(acc[2][1] + xi1.z + bias4.z);
        h1v.w = tanhf(acc[3][1] + xi1.w + bias4.w);
        float* dst = h0b + (t & 1) * 16384;
        STG_C(dst + (size_t)(fb2 + 0) * HD + col0 + cg * 4, h0v);
        STG_C(dst + (size_t)(fb2 + 1) * HD + col0 + cg * 4, h1v);
        if (t == LS - 1) {  // h_final L0 (plain stores, host-visible at end)
          *(f32x4*)(outbuf + OUT0 + (size_t)(fb2 + 0) * HD + col0 + cg * 4) = h0v;
          *(f32x4*)(outbuf + OUT0 + (size_t)(fb2 + 1) * HD + col0 + cg * 4) = h1v;
        }
      }
      // Drain our sc1 stores (inline-asm stores are invisible to the
      // compiler's waitcnt tracking — explicit vmcnt(0) required), then
      // barrier, then publish.
      asm volatile("s_waitcnt vmcnt(0)" ::: "memory");
      __syncthreads();
      if (tid == 0)
        __hip_atomic_store(stampL0 + cb2, (unsigned)(t + 1),
                           __ATOMIC_RELAXED, __HIP_MEMORY_SCOPE_AGENT);
    }
  } else {
    const int m = st >> 7;                 // 0 = Wi1 (reads h0), 1 = Wh1 (reads h1)
    const int r = st & 127;
    const int cg = r & 1;
    const int ks = (r >> 1) & 15;
    const int kb = ks * 32;
    const int bg = r >> 5;                 // 4 b-groups of 4
    float4 w[4][8];
    const float* Wm = WT + (size_t)(1 + m) * HD * HD;
#pragma unroll
    for (int ci = 0; ci < 4; ++ci)
#pragma unroll
      for (int kk = 0; kk < 8; ++kk)
        w[ci][kk] = *(const float4*)(Wm + (size_t)(col0 + cg * 4 + ci) * HD + kb + kk * 4);
    float fbias = 0.f;
    const int fco = st & 7;
    const int fbo = st >> 3;
    const int fcol = col0 + fco;
    const int fb = bbase + fbo;
    if (st < 128) fbias = bi1[fcol] + bh1[fcol];

    for (int t = 0; t < LS; ++t) {
      // h1[t-1] is guarded by OWN stamps only — issue its loads first, so
      // their latency hides under the wait for L0's h0[t] stamp.
      wave_poll(stampL1, t);
      const float* s1 = h1b + ((t + 1) & 1) * 16384 + bbase * HD;
      f32x4 e, f, g2, h;
      LDG_C(e, s1 + ((0 * 512 + tid) << 2));
      LDG_C(f, s1 + ((1 * 512 + tid) << 2));
      LDG_C(g2, s1 + ((2 * 512 + tid) << 2));
      LDG_C(h, s1 + ((3 * 512 + tid) << 2));

      wave_poll(stampL0, t + 1);           // h0[t] published by all L0(g)
      const float* s0 = h0b + (t & 1) * 16384 + bbase * HD;
      f32x4 a, b, c, d;
      LDG_C(a, s0 + ((0 * 512 + tid) << 2));
      LDG_C(b, s0 + ((1 * 512 + tid) << 2));
      LDG_C(c, s0 + ((2 * 512 + tid) << 2));
      LDG_C(d, s0 + ((3 * 512 + tid) << 2));
      asm volatile("s_waitcnt vmcnt(0)" ::: "memory");
      *(f32x4*)&hst0[swz(0 * 512 + tid)] = a;
      *(f32x4*)&hst0[swz(1 * 512 + tid)] = b;
      *(f32x4*)&hst0[swz(2 * 512 + tid)] = c;
      *(f32x4*)&hst0[swz(3 * 512 + tid)] = d;
      *(f32x4*)&hst1[swz(0 * 512 + tid)] = e;
      *(f32x4*)&hst1[swz(1 * 512 + tid)] = f;
      *(f32x4*)&hst1[swz(2 * 512 + tid)] = g2;
      *(f32x4*)&hst1[swz(3 * 512 + tid)] = h;
      __syncthreads();

      const float* hbase = (m == 0) ? hst0 : hst1;
      float acc[4][4] = {};
#pragma unroll
      for (int bj = 0; bj < 4; ++bj) {
        const float* hr = hbase + (bg * 4 + bj) * HSTRIDE + ks * 36;
#pragma unroll
        for (int kk = 0; kk < 8; ++kk) {
          const float4 h4 = *(const float4*)(hr + kk * 4);
#pragma unroll
          for (int ci = 0; ci < 4; ++ci) {
            const float4 wv = w[ci][kk];
            acc[ci][bj] = fmaf(wv.x, h4.x, acc[ci][bj]);
            acc[ci][bj] = fmaf(wv.y, h4.y, acc[ci][bj]);
            acc[ci][bj] = fmaf(wv.z, h4.z, acc[ci][bj]);
            acc[ci][bj] = fmaf(wv.w, h4.w, acc[ci][bj]);
          }
        }
      }
#pragma unroll
      for (int ci = 0; ci < 4; ++ci)
#pragma unroll
        for (int bj = 0; bj < 4; ++bj)
          part[((bg * 4 + bj) * 8 + cg * 4 + ci) * 36 + m * 16 + ks] = acc[ci][bj];
      __syncthreads();
      if (st < 128) {
        const float4* pp = (const float4*)&part[st * 36];
        float sv = fbias;
#pragma unroll
        for (int j = 0; j < 8; ++j) {
          const float4 p = pp[j];
          sv += ((p.x + p.y) + (p.z + p.w));
        }
        const float hv = tanhf(sv);
        __hip_atomic_store((unsigned*)(h1b + (t & 1) * 16384 + (size_t)fb * HD + fcol),
                           __builtin_bit_cast(unsigned, hv),
                           __ATOMIC_RELAXED, __HIP_MEMORY_SCOPE_AGENT);
        outbuf[((size_t)fb * LS + t) * HD + fcol] = hv;
        if (t == LS - 1) outbuf[OUT0 + NB * HD + (size_t)fb * HD + fcol] = hv;  // h_final L1
      }
      __syncthreads();  // drains the atomic h1 stores (compiler-known)
      if (tid == 0)
        __hip_atomic_store(stampL1 + cb2, (unsigned)(t + 1),
                           __ATOMIC_RELAXED, __HIP_MEMORY_SCOPE_AGENT);
    }
  }
}

// ---------------------------------------------------------------------------
// ws layout (floats): [0,65536) h dbufs; [65536,65536+786432) WT;
// [SYNC_OFF, SYNC_OFF+256) per-block progress stamps (u32, 128 used).
// ---------------------------------------------------------------------------
extern "C" void kernel_launch(void* const* d_in, const int* in_sizes, int n_in,
                              void* d_out, int out_size, void* d_ws, size_t ws_size,
                              hipStream_t stream) {
  const float* x  = (const float*)d_in[0];
  const float* h0 = (const float*)d_in[1];
  const float* Wi = (const float*)d_in[2];
  const float* bi = (const float*)d_in[3];
  const float* Wh = (const float*)d_in[4];
  const float* bh = (const float*)d_in[5];
  float* out = (float*)d_out;
  float* ws  = (float*)d_ws;

  const float* Wi0 = Wi;
  const float* Wi1 = Wi + (size_t)HD * HD;
  const float* bi0 = bi;
  const float* bi1 = bi + HD;
  const float* Wh0 = Wh;
  const float* Wh1 = Wh + (size_t)HD * HD;
  const float* bh0 = bh;
  const float* bh1 = bh + HD;

  const float* WT = ws + 65536;

  static int attr_set = 0;
  if (!attr_set) {
    hipFuncSetAttribute((const void*)rnn_persist,
                        hipFuncAttributeMaxDynamicSharedMemorySize, SMEM_BYTES);
    attr_set = 1;
  }

  xi_gemm<<<dim3(8, 1024), 256, 0, stream>>>(x, Wi0, bi0, out);
  transpose_w<<<dim3(2, 512, 3), 256, 0, stream>>>(Wh0, Wi1, Wh1, ws + 65536);
  init_h<<<128, 256, 0, stream>>>(h0, ws);

  void* kargs[] = {(void*)&WT, (void*)&bh0, (void*)&bi1, (void*)&bh1,
                   (void*)&out, (void*)&ws};
  hipLaunchCooperativeKernel((const void*)rnn_persist, dim3(128), dim3(512),
                             kargs, SMEM_BYTES, stream);
}